// Round 3
// baseline (726.926 us; speedup 1.0000x reference)
//
#include <hip/hip_runtime.h>
#include <math.h>

#define LSEQ 512
#define DG 256
#define DB 128
#define NH 8
#define HD 32
#define EPSV 1e-5f
#define LP2 516          // logits LDS row stride (pad vs 512 to break bank alignment)

typedef __attribute__((ext_vector_type(8))) short bf16x8;
typedef __attribute__((ext_vector_type(4))) float f32x4;

__device__ __forceinline__ unsigned short f2bf(float x) {
    unsigned int u = __float_as_uint(x);
    u += 0x7FFFu + ((u >> 16) & 1u);       // RNE
    return (unsigned short)(u >> 16);
}
__device__ __forceinline__ float bf2f(unsigned short h) {
    return __uint_as_float(((unsigned int)h) << 16);
}

// ---------------------------------------------------------------------------
// Kernel 1: layernorm(x) + Q/K/V/Gate projections. 256 blocks x 256 thr.
// Must precede the fused kernel (its QK^T phase reads q_ws/k_ws).
// ---------------------------------------------------------------------------
__global__ __launch_bounds__(256) void prep_kernel(
    const float* __restrict__ x, const float* __restrict__ g_gamma,
    const float* __restrict__ g_beta, const float* __restrict__ Wq,
    const float* __restrict__ Wk, const float* __restrict__ Wv,
    const float* __restrict__ Wg, const float* __restrict__ bg,
    float* __restrict__ q_ws, float* __restrict__ k_ws,
    float* __restrict__ v_ws, float* __restrict__ g_ws)
{
    __shared__ float xs[4][DG];
    const int t = threadIdx.x;
    const int wave = t >> 6, lane = t & 63;
    const int row0 = blockIdx.x << 2;

    {   // one wave per row: layernorm over 256
        const int row = row0 + wave;
        const float4 xv = *(const float4*)(x + (size_t)row * DG + lane * 4);
        float s  = xv.x + xv.y + xv.z + xv.w;
        float ss = xv.x*xv.x + xv.y*xv.y + xv.z*xv.z + xv.w*xv.w;
        #pragma unroll
        for (int m = 32; m >= 1; m >>= 1) { s += __shfl_xor(s, m); ss += __shfl_xor(ss, m); }
        const float mean = s * (1.f / DG);
        const float rstd = rsqrtf(ss * (1.f / DG) - mean * mean + EPSV);
        const float4 gg = *(const float4*)(g_gamma + lane * 4);
        const float4 gb = *(const float4*)(g_beta + lane * 4);
        float4 xo;
        xo.x = (xv.x - mean) * rstd * gg.x + gb.x;
        xo.y = (xv.y - mean) * rstd * gg.y + gb.y;
        xo.z = (xv.z - mean) * rstd * gg.z + gb.z;
        xo.w = (xv.w - mean) * rstd * gg.w + gb.w;
        *(float4*)&xs[wave][lane * 4] = xo;
    }
    __syncthreads();

    float aq[4] = {0,0,0,0}, ak[4] = {0,0,0,0}, av[4] = {0,0,0,0}, ag[4] = {0,0,0,0};
    #pragma unroll 4
    for (int c = 0; c < DG; ++c) {
        const float wq = Wq[(size_t)c * DG + t];
        const float wk = Wk[(size_t)c * DG + t];
        const float wv = Wv[(size_t)c * DG + t];
        const float wg = Wg[(size_t)c * DG + t];
        #pragma unroll
        for (int r = 0; r < 4; ++r) {
            const float xr = xs[r][c];
            aq[r] = fmaf(xr, wq, aq[r]);
            ak[r] = fmaf(xr, wk, ak[r]);
            av[r] = fmaf(xr, wv, av[r]);
            ag[r] = fmaf(xr, wg, ag[r]);
        }
    }

    const float scal = 0.17677669529663687f;  // 1/sqrt(32)
    const float bgv = bg[t];
    #pragma unroll
    for (int r = 0; r < 4; ++r) {
        const size_t o = (size_t)(row0 + r) * DG + t;
        q_ws[o] = aq[r];
        k_ws[o] = ak[r] * scal;
        v_ws[o] = av[r];
        g_ws[o] = 1.f / (1.f + __expf(-(ag[r] + bgv)));
    }
}

// ---------------------------------------------------------------------------
// Kernel 2 (fused): one block per (b,q). Bias layernorm+@Wb streams straight
// into the logits LDS; QK^T overlaps the initial load latency; softmax, PV,
// gate and @Wout finish in-block. pair_ws round-trip eliminated.
// 1024 blocks x 256 thr, ~117 KB LDS -> 1 block/CU, 3-deep staging prefetch.
// ---------------------------------------------------------------------------
__global__ __launch_bounds__(256) void fused_kernel(
    const float* __restrict__ bias, const float* __restrict__ b_gamma,
    const float* __restrict__ b_beta, const float* __restrict__ Wb,
    const float* __restrict__ Wout, const float* __restrict__ bout,
    const float* __restrict__ q_ws, const float* __restrict__ k_ws,
    const float* __restrict__ v_ws, const float* __restrict__ g_ws,
    float* __restrict__ out)
{
    __shared__ float stg[4 * 3 * 2048];    // 96 KB: [wave][3 bufs][16 rows*128]
    __shared__ float lg[NH * LP2];         // 16.5 KB logits [h][k]
    __shared__ float ps[4 * 64 * 4];       // PV partials [s4][c4]f4, 4 KB
    __shared__ float row_s[DG];
    __shared__ float rden[NH];

    const int t = threadIdx.x;
    const int w = t >> 6, l = t & 63;
    const int n = l & 15, quad = l >> 4;
    const int bq = blockIdx.x;             // = b*512 + q
    const int b = bq >> 9;

    // B-fragments (constant): gw = gamma*Wb, split hi/lo.
    // col n==8 of gwhi = 1.0 -> MFMA also produces row sums at n=8.
    bf16x8 gwhi[4], gwlo[4];
    float S1 = 0.f, S0 = 0.f;
    #pragma unroll
    for (int ks = 0; ks < 4; ++ks) {
        #pragma unroll
        for (int j = 0; j < 8; ++j) {
            const int c = ks * 32 + quad * 8 + j;
            const float wb = (n < 8) ? Wb[c * 8 + n] : 0.f;
            const float wv = b_gamma[c] * wb;
            S1 += wv;
            S0 += b_beta[c] * wb;
            unsigned short hi = f2bf(wv);
            unsigned short lo = f2bf(wv - bf2f(hi));
            if (n == 8) { hi = 0x3F80; lo = 0; }   // ones column
            gwhi[ks][j] = (short)hi;
            gwlo[ks][j] = (short)lo;
        }
    }
    S1 += __shfl_xor(S1, 16); S1 += __shfl_xor(S1, 32);
    S0 += __shfl_xor(S0, 16); S0 += __shfl_xor(S0, 32);

    float* myl = stg + w * 6144;                       // my 3 buffers
    const size_t rowbase = (size_t)bq * LSEQ + w * 16; // this wave's bias rows

    auto stage = [&](int tt) {
        const float* src = bias + (rowbase + (size_t)tt * 64) * DB;
        float* dst = myl + (tt % 3) * 2048;
        #pragma unroll
        for (int i = 0; i < 8; ++i) {
            __builtin_amdgcn_global_load_lds(
                (const __attribute__((address_space(1))) void*)(src + i * 256 + l * 4),
                (__attribute__((address_space(3))) void*)(dst + i * 256 + l * 4),
                16, 0, 0);
        }
    };

    auto compute = [&](int tt) {
        const float* d = myl + (tt % 3) * 2048 + n * 128 + quad * 8;
        f32x4 acc = {0.f, 0.f, 0.f, 0.f};
        float ssq = 0.f;
        #pragma unroll
        for (int ks = 0; ks < 4; ++ks) {
            const float4 x0 = *(const float4*)(d + ks * 32);
            const float4 x1 = *(const float4*)(d + ks * 32 + 4);
            ssq = fmaf(x0.x,x0.x, fmaf(x0.y,x0.y, fmaf(x0.z,x0.z, fmaf(x0.w,x0.w, ssq))));
            ssq = fmaf(x1.x,x1.x, fmaf(x1.y,x1.y, fmaf(x1.z,x1.z, fmaf(x1.w,x1.w, ssq))));
            const float xsv[8] = {x0.x,x0.y,x0.z,x0.w,x1.x,x1.y,x1.z,x1.w};
            bf16x8 ahi, alo;
            #pragma unroll
            for (int j = 0; j < 8; ++j) {
                const unsigned short hi = f2bf(xsv[j]);
                ahi[j] = (short)hi;
                alo[j] = (short)f2bf(xsv[j] - bf2f(hi));
            }
            acc = __builtin_amdgcn_mfma_f32_16x16x32_bf16(ahi, gwhi[ks], acc, 0, 0, 0);
            acc = __builtin_amdgcn_mfma_f32_16x16x32_bf16(alo, gwhi[ks], acc, 0, 0, 0);
            acc = __builtin_amdgcn_mfma_f32_16x16x32_bf16(ahi, gwlo[ks], acc, 0, 0, 0);
        }
        ssq += __shfl_xor(ssq, 16);
        ssq += __shfl_xor(ssq, 32);
        // D layout: row=(quad*4+reg), col=n. Row sums at lane quad*16+8.
        // k index of row = w*16 + tt*64 + quad*4 + reg; h = n.
        float* pl = lg + n * LP2 + (w * 16 + tt * 64 + quad * 4);
        #pragma unroll
        for (int reg = 0; reg < 4; ++reg) {
            const float sumr = __uint_as_float((unsigned)__builtin_amdgcn_ds_bpermute(
                (quad * 16 + 8) * 4, (int)__float_as_uint(acc[reg])));
            const float ssqr = __uint_as_float((unsigned)__builtin_amdgcn_ds_bpermute(
                (quad * 4 + reg) * 4, (int)__float_as_uint(ssq)));
            const float mean = sumr * (1.f / DB);
            const float var  = ssqr * (1.f / DB) - mean * mean;
            const float rstd = rsqrtf(var + EPSV);
            const float p = rstd * (acc[reg] - mean * S1) + S0;
            if (n < NH) pl[reg] += p;
        }
    };

    // ---- issue 3 tiles of prefetch, then QK^T under the load latency ----
    stage(0); stage(1); stage(2);

    {   // QK^T: wave w handles h = 2w, 2w+1. Coalesced: 8 rows x 128B/instr.
        const int d4 = l >> 3, r = l & 7;
        #pragma unroll
        for (int p = 0; p < 2; ++p) {
            const int h = w * 2 + p;
            const float4 qa = *(const float4*)(q_ws + (size_t)bq * DG + h * HD + d4 * 4);
            const float* kbase = k_ws + ((size_t)(b * LSEQ)) * DG + h * HD + d4 * 4;
            float* lrow = lg + h * LP2;
            #pragma unroll 4
            for (int kb8 = 0; kb8 < 64; ++kb8) {
                const int krow = kb8 * 8 + r;
                const float4 kv = *(const float4*)(kbase + (size_t)krow * DG);
                float a0 = fmaf(kv.x, qa.x, fmaf(kv.y, qa.y, fmaf(kv.z, qa.z, kv.w * qa.w)));
                a0 += __shfl_xor(a0, 8);
                a0 += __shfl_xor(a0, 16);
                a0 += __shfl_xor(a0, 32);
                if (d4 == 0) lrow[krow] = a0;     // init lg with qk logits
            }
        }
    }
    __syncthreads();   // lg fully initialized (barrier also drains prefetch)

    // ---- bias stream: compute tile tt, then refill its buffer with tt+3 ----
    #pragma unroll
    for (int tt = 0; tt < 8; ++tt) {
        if (tt <= 5)      asm volatile("s_waitcnt vmcnt(16)" ::: "memory");
        else if (tt == 6) asm volatile("s_waitcnt vmcnt(8)"  ::: "memory");
        else              asm volatile("s_waitcnt vmcnt(0)"  ::: "memory");
        compute(tt);
        if (tt + 3 < 8) {
            asm volatile("s_waitcnt lgkmcnt(0)" ::: "memory");  // buf reads done
            stage(tt + 3);
        }
    }
    __syncthreads();

    // ---- softmax over k per h: 32 lanes per h ----
    {
        const int qh = t >> 5, l32 = t & 31;
        float* lrow = lg + qh * LP2;
        float mx = -1e30f;
        #pragma unroll
        for (int i = 0; i < 16; ++i) mx = fmaxf(mx, lrow[l32 + i * 32]);
        #pragma unroll
        for (int m = 16; m >= 1; m >>= 1) mx = fmaxf(mx, __shfl_xor(mx, m));
        float s = 0.f;
        #pragma unroll
        for (int i = 0; i < 16; ++i) {
            const int k = l32 + i * 32;
            const float e = __expf(lrow[k] - mx);
            lrow[k] = e;
            s += e;
        }
        #pragma unroll
        for (int m = 16; m >= 1; m >>= 1) s += __shfl_xor(s, m);
        if (l32 == 0) rden[qh] = 1.f / s;
    }
    __syncthreads();

    // ---- PV, k split 4 ways ----
    {
        const int s4 = t >> 6, c4 = t & 63;
        const int h = c4 >> 3;
        const float* vb = v_ws + ((size_t)(b * LSEQ + s4 * 128)) * DG + c4 * 4;
        const float* prow = lg + h * LP2 + s4 * 128;
        float4 a = {0.f, 0.f, 0.f, 0.f};
        #pragma unroll 4
        for (int i = 0; i < 128; ++i) {
            const float p = prow[i];
            const float4 vv = *(const float4*)(vb + (size_t)i * DG);
            a.x = fmaf(p, vv.x, a.x);
            a.y = fmaf(p, vv.y, a.y);
            a.z = fmaf(p, vv.z, a.z);
            a.w = fmaf(p, vv.w, a.w);
        }
        *(float4*)&ps[(s4 * 64 + c4) * 4] = a;
    }
    __syncthreads();
    if (t < 64) {
        const int c4 = t, h = c4 >> 3;
        float4 a = *(const float4*)&ps[(0 * 64 + c4) * 4];
        #pragma unroll
        for (int s4 = 1; s4 < 4; ++s4) {
            const float4 p4 = *(const float4*)&ps[(s4 * 64 + c4) * 4];
            a.x += p4.x; a.y += p4.y; a.z += p4.z; a.w += p4.w;
        }
        const float sc = rden[h];
        const float4 g4 = *(const float4*)(g_ws + (size_t)bq * DG + c4 * 4);
        float* rs = row_s + c4 * 4;
        rs[0] = a.x * sc * g4.x;
        rs[1] = a.y * sc * g4.y;
        rs[2] = a.z * sc * g4.z;
        rs[3] = a.w * sc * g4.w;
    }
    __syncthreads();

    // ---- row_s @ Wout + bout ----
    {
        const int co = t;
        const float* wo = Wout + co;
        float a = 0.f;
        #pragma unroll 4
        for (int c = 0; c < DG; ++c)
            a = fmaf(row_s[c], wo[(size_t)c * DG], a);
        out[(size_t)bq * DG + co] = a + bout[co];
    }
}

extern "C" void kernel_launch(void* const* d_in, const int* in_sizes, int n_in,
                              void* d_out, int out_size, void* d_ws, size_t ws_size,
                              hipStream_t stream)
{
    const float* x       = (const float*)d_in[0];
    const float* bias    = (const float*)d_in[1];
    const float* g_gamma = (const float*)d_in[2];
    const float* g_beta  = (const float*)d_in[3];
    const float* b_gamma = (const float*)d_in[4];
    const float* b_beta  = (const float*)d_in[5];
    const float* Wq      = (const float*)d_in[6];
    const float* Wk      = (const float*)d_in[7];
    const float* Wv      = (const float*)d_in[8];
    const float* Wb      = (const float*)d_in[9];
    const float* Wg      = (const float*)d_in[10];
    const float* bg      = (const float*)d_in[11];
    const float* Wout    = (const float*)d_in[12];
    const float* bout    = (const float*)d_in[13];
    float* out = (float*)d_out;

    float* ws   = (float*)d_ws;
    float* q_ws = ws;                    // 1 MB each
    float* k_ws = ws + 262144;
    float* v_ws = ws + 2 * 262144;
    float* g_ws = ws + 3 * 262144;

    hipLaunchKernelGGL(prep_kernel, dim3(256), dim3(256), 0, stream,
                       x, g_gamma, g_beta, Wq, Wk, Wv, Wg, bg,
                       q_ws, k_ws, v_ws, g_ws);
    hipLaunchKernelGGL(fused_kernel, dim3(1024), dim3(256), 0, stream,
                       bias, b_gamma, b_beta, Wb, Wout, bout,
                       q_ws, k_ws, v_ws, g_ws, out);
}

// Round 4
// 548.365 us; speedup vs baseline: 1.3256x; 1.3256x over previous
//
#include <hip/hip_runtime.h>
#include <math.h>

#define LSEQ 512
#define DG 256
#define DB 128
#define NH 8
#define HD 32
#define EPSV 1e-5f
#define LP2 516          // logits LDS row stride

typedef __attribute__((ext_vector_type(8))) short bf16x8;
typedef __attribute__((ext_vector_type(4))) float f32x4;

__device__ __forceinline__ unsigned short f2bf(float x) {
    unsigned int u = __float_as_uint(x);
    u += 0x7FFFu + ((u >> 16) & 1u);       // RNE
    return (unsigned short)(u >> 16);
}
__device__ __forceinline__ float bf2f(unsigned short h) {
    return __uint_as_float(((unsigned int)h) << 16);
}

// ---------------------------------------------------------------------------
// Kernel 1: layernorm(x) + Q/K/V/Gate projections. 256 blocks x 256 thr.
// ---------------------------------------------------------------------------
__global__ __launch_bounds__(256) void prep_kernel(
    const float* __restrict__ x, const float* __restrict__ g_gamma,
    const float* __restrict__ g_beta, const float* __restrict__ Wq,
    const float* __restrict__ Wk, const float* __restrict__ Wv,
    const float* __restrict__ Wg, const float* __restrict__ bg,
    float* __restrict__ q_ws, float* __restrict__ k_ws,
    float* __restrict__ v_ws, float* __restrict__ g_ws)
{
    __shared__ float xs[4][DG];
    const int t = threadIdx.x;
    const int wave = t >> 6, lane = t & 63;
    const int row0 = blockIdx.x << 2;

    {   // one wave per row: layernorm over 256
        const int row = row0 + wave;
        const float4 xv = *(const float4*)(x + (size_t)row * DG + lane * 4);
        float s  = xv.x + xv.y + xv.z + xv.w;
        float ss = xv.x*xv.x + xv.y*xv.y + xv.z*xv.z + xv.w*xv.w;
        #pragma unroll
        for (int m = 32; m >= 1; m >>= 1) { s += __shfl_xor(s, m); ss += __shfl_xor(ss, m); }
        const float mean = s * (1.f / DG);
        const float rstd = rsqrtf(ss * (1.f / DG) - mean * mean + EPSV);
        const float4 gg = *(const float4*)(g_gamma + lane * 4);
        const float4 gb = *(const float4*)(g_beta + lane * 4);
        float4 xo;
        xo.x = (xv.x - mean) * rstd * gg.x + gb.x;
        xo.y = (xv.y - mean) * rstd * gg.y + gb.y;
        xo.z = (xv.z - mean) * rstd * gg.z + gb.z;
        xo.w = (xv.w - mean) * rstd * gg.w + gb.w;
        *(float4*)&xs[wave][lane * 4] = xo;
    }
    __syncthreads();

    float aq[4] = {0,0,0,0}, ak[4] = {0,0,0,0}, av[4] = {0,0,0,0}, ag[4] = {0,0,0,0};
    #pragma unroll 4
    for (int c = 0; c < DG; ++c) {
        const float wq = Wq[(size_t)c * DG + t];
        const float wk = Wk[(size_t)c * DG + t];
        const float wv = Wv[(size_t)c * DG + t];
        const float wg = Wg[(size_t)c * DG + t];
        #pragma unroll
        for (int r = 0; r < 4; ++r) {
            const float xr = xs[r][c];
            aq[r] = fmaf(xr, wq, aq[r]);
            ak[r] = fmaf(xr, wk, ak[r]);
            av[r] = fmaf(xr, wv, av[r]);
            ag[r] = fmaf(xr, wg, ag[r]);
        }
    }

    const float scal = 0.17677669529663687f;  // 1/sqrt(32)
    const float bgv = bg[t];
    #pragma unroll
    for (int r = 0; r < 4; ++r) {
        const size_t o = (size_t)(row0 + r) * DG + t;
        q_ws[o] = aq[r];
        k_ws[o] = ak[r] * scal;
        v_ws[o] = av[r];
        g_ws[o] = 1.f / (1.f + __expf(-(ag[r] + bgv)));
    }
}

// ---------------------------------------------------------------------------
// Kernel 2 (fused): one block per (b,q). ~48 KB LDS -> 3 blocks/CU
// (12 waves/CU): TLP hides the stream + phase latencies (round-3 post-mortem:
// 120 KB LDS -> 1 wave/SIMD -> 90% stall). Single staging buffer, barrier-
// free per-wave stream; post-stream scratch aliases the dead staging region.
// ---------------------------------------------------------------------------
__global__ __launch_bounds__(256, 3) void fused_kernel(
    const float* __restrict__ bias, const float* __restrict__ b_gamma,
    const float* __restrict__ b_beta, const float* __restrict__ Wb,
    const float* __restrict__ Wout, const float* __restrict__ bout,
    const float* __restrict__ q_ws, const float* __restrict__ k_ws,
    const float* __restrict__ v_ws, const float* __restrict__ g_ws,
    float* __restrict__ out)
{
    __shared__ float stg[4 * 2048];        // 32 KB: [wave][16 rows * 128]
    __shared__ float lg[NH * LP2];         // 16.5 KB logits [h][k]
    // post-stream scratch aliases stg (dead after the stream loop):
    float* ps    = stg;                    // [4][64][4] = 1024 floats
    float* row_s = stg + 1024;             // [256]
    float* rden  = stg + 1280;             // [8]

    const int t = threadIdx.x;
    const int w = t >> 6, l = t & 63;
    const int n = l & 15, quad = l >> 4;
    const int bq = blockIdx.x;             // = b*512 + q
    const int b = bq >> 9;

    // B-fragments (constant): gw = gamma*Wb, split hi/lo.
    // col n==8 of gwhi = 1.0 -> MFMA also produces row sums at n=8.
    bf16x8 gwhi[4], gwlo[4];
    float S1 = 0.f, S0 = 0.f;
    #pragma unroll
    for (int ks = 0; ks < 4; ++ks) {
        #pragma unroll
        for (int j = 0; j < 8; ++j) {
            const int c = ks * 32 + quad * 8 + j;
            const float wb = (n < 8) ? Wb[c * 8 + n] : 0.f;
            const float wv = b_gamma[c] * wb;
            S1 += wv;
            S0 += b_beta[c] * wb;
            unsigned short hi = f2bf(wv);
            unsigned short lo = f2bf(wv - bf2f(hi));
            if (n == 8) { hi = 0x3F80; lo = 0; }   // ones column
            gwhi[ks][j] = (short)hi;
            gwlo[ks][j] = (short)lo;
        }
    }
    S1 += __shfl_xor(S1, 16); S1 += __shfl_xor(S1, 32);
    S0 += __shfl_xor(S0, 16); S0 += __shfl_xor(S0, 32);

    float* myl = stg + w * 2048;                       // my 16-row buffer
    const size_t rowbase = (size_t)bq * LSEQ + w * 16; // this wave's bias rows

    auto stage = [&](int tt) {
        const float* src = bias + (rowbase + (size_t)tt * 64) * DB;
        #pragma unroll
        for (int i = 0; i < 8; ++i) {
            __builtin_amdgcn_global_load_lds(
                (const __attribute__((address_space(1))) void*)(src + i * 256 + l * 4),
                (__attribute__((address_space(3))) void*)(myl + i * 256 + l * 4),
                16, 0, 0);
        }
    };

    auto compute = [&](int tt) {
        const float* d = myl + n * 128 + quad * 8;
        f32x4 acc = {0.f, 0.f, 0.f, 0.f};
        float ssq = 0.f;
        #pragma unroll
        for (int ks = 0; ks < 4; ++ks) {
            const float4 x0 = *(const float4*)(d + ks * 32);
            const float4 x1 = *(const float4*)(d + ks * 32 + 4);
            ssq = fmaf(x0.x,x0.x, fmaf(x0.y,x0.y, fmaf(x0.z,x0.z, fmaf(x0.w,x0.w, ssq))));
            ssq = fmaf(x1.x,x1.x, fmaf(x1.y,x1.y, fmaf(x1.z,x1.z, fmaf(x1.w,x1.w, ssq))));
            const float xsv[8] = {x0.x,x0.y,x0.z,x0.w,x1.x,x1.y,x1.z,x1.w};
            bf16x8 ahi, alo;
            #pragma unroll
            for (int j = 0; j < 8; ++j) {
                const unsigned short hi = f2bf(xsv[j]);
                ahi[j] = (short)hi;
                alo[j] = (short)f2bf(xsv[j] - bf2f(hi));
            }
            acc = __builtin_amdgcn_mfma_f32_16x16x32_bf16(ahi, gwhi[ks], acc, 0, 0, 0);
            acc = __builtin_amdgcn_mfma_f32_16x16x32_bf16(alo, gwhi[ks], acc, 0, 0, 0);
            acc = __builtin_amdgcn_mfma_f32_16x16x32_bf16(ahi, gwlo[ks], acc, 0, 0, 0);
        }
        ssq += __shfl_xor(ssq, 16);
        ssq += __shfl_xor(ssq, 32);
        // D layout: row=(quad*4+reg), col=n. Row sums at lane quad*16+8.
        // k index of row = w*16 + tt*64 + quad*4 + reg; h = n.
        float* pl = lg + n * LP2 + (w * 16 + tt * 64 + quad * 4);
        #pragma unroll
        for (int reg = 0; reg < 4; ++reg) {
            const float sumr = __uint_as_float((unsigned)__builtin_amdgcn_ds_bpermute(
                (quad * 16 + 8) * 4, (int)__float_as_uint(acc[reg])));
            const float ssqr = __uint_as_float((unsigned)__builtin_amdgcn_ds_bpermute(
                (quad * 4 + reg) * 4, (int)__float_as_uint(ssq)));
            const float mean = sumr * (1.f / DB);
            const float var  = ssqr * (1.f / DB) - mean * mean;
            const float rstd = rsqrtf(var + EPSV);
            const float p = rstd * (acc[reg] - mean * S1) + S0;
            if (n < NH) pl[reg] += p;
        }
    };

    // ---- prefetch tile 0, then QK^T under the load latency ----
    stage(0);

    {   // QK^T: wave w handles h = 2w, 2w+1. Coalesced: 8 rows x 128B/instr.
        const int d4 = l >> 3, r = l & 7;
        #pragma unroll
        for (int p = 0; p < 2; ++p) {
            const int h = w * 2 + p;
            const float4 qa = *(const float4*)(q_ws + (size_t)bq * DG + h * HD + d4 * 4);
            const float* kbase = k_ws + ((size_t)(b * LSEQ)) * DG + h * HD + d4 * 4;
            float* lrow = lg + h * LP2;
            #pragma unroll 8
            for (int kb8 = 0; kb8 < 64; ++kb8) {
                const int krow = kb8 * 8 + r;
                const float4 kv = *(const float4*)(kbase + (size_t)krow * DG);
                float a0 = fmaf(kv.x, qa.x, fmaf(kv.y, qa.y, fmaf(kv.z, qa.z, kv.w * qa.w)));
                a0 += __shfl_xor(a0, 8);
                a0 += __shfl_xor(a0, 16);
                a0 += __shfl_xor(a0, 32);
                if (d4 == 0) lrow[krow] = a0;     // init lg with qk logits
            }
        }
    }
    __syncthreads();   // all lg rows initialized before any wave's compute()

    // ---- bias stream: per-wave, barrier-free (each wave owns its k-slice) ----
    #pragma unroll
    for (int tt = 0; tt < 8; ++tt) {
        asm volatile("s_waitcnt vmcnt(0)" ::: "memory");    // tile tt landed
        compute(tt);
        if (tt < 7) {
            asm volatile("s_waitcnt lgkmcnt(0)" ::: "memory"); // buf reads done
            stage(tt + 1);
        }
    }
    __syncthreads();   // stream + lg updates complete; stg now dead

    // ---- softmax over k per h: 32 lanes per h ----
    {
        const int qh = t >> 5, l32 = t & 31;
        float* lrow = lg + qh * LP2;
        float mx = -1e30f;
        #pragma unroll
        for (int i = 0; i < 16; ++i) mx = fmaxf(mx, lrow[l32 + i * 32]);
        #pragma unroll
        for (int m = 16; m >= 1; m >>= 1) mx = fmaxf(mx, __shfl_xor(mx, m));
        float s = 0.f;
        #pragma unroll
        for (int i = 0; i < 16; ++i) {
            const int k = l32 + i * 32;
            const float e = __expf(lrow[k] - mx);
            lrow[k] = e;
            s += e;
        }
        #pragma unroll
        for (int m = 16; m >= 1; m >>= 1) s += __shfl_xor(s, m);
        if (l32 == 0) rden[qh] = 1.f / s;
    }
    __syncthreads();

    // ---- PV, k split 4 ways ----
    {
        const int s4 = t >> 6, c4 = t & 63;
        const int h = c4 >> 3;
        const float* vb = v_ws + ((size_t)(b * LSEQ + s4 * 128)) * DG + c4 * 4;
        const float* prow = lg + h * LP2 + s4 * 128;
        float4 a = {0.f, 0.f, 0.f, 0.f};
        #pragma unroll 8
        for (int i = 0; i < 128; ++i) {
            const float p = prow[i];
            const float4 vv = *(const float4*)(vb + (size_t)i * DG);
            a.x = fmaf(p, vv.x, a.x);
            a.y = fmaf(p, vv.y, a.y);
            a.z = fmaf(p, vv.z, a.z);
            a.w = fmaf(p, vv.w, a.w);
        }
        *(float4*)&ps[(s4 * 64 + c4) * 4] = a;
    }
    __syncthreads();
    if (t < 64) {
        const int c4 = t, h = c4 >> 3;
        float4 a = *(const float4*)&ps[(0 * 64 + c4) * 4];
        #pragma unroll
        for (int s4 = 1; s4 < 4; ++s4) {
            const float4 p4 = *(const float4*)&ps[(s4 * 64 + c4) * 4];
            a.x += p4.x; a.y += p4.y; a.z += p4.z; a.w += p4.w;
        }
        const float sc = rden[h];
        const float4 g4 = *(const float4*)(g_ws + (size_t)bq * DG + c4 * 4);
        float* rs = row_s + c4 * 4;
        rs[0] = a.x * sc * g4.x;
        rs[1] = a.y * sc * g4.y;
        rs[2] = a.z * sc * g4.z;
        rs[3] = a.w * sc * g4.w;
    }
    __syncthreads();

    // ---- row_s @ Wout + bout ----
    {
        const int co = t;
        const float* wo = Wout + co;
        float a = 0.f;
        #pragma unroll 8
        for (int c = 0; c < DG; ++c)
            a = fmaf(row_s[c], wo[(size_t)c * DG], a);
        out[(size_t)bq * DG + co] = a + bout[co];
    }
}

extern "C" void kernel_launch(void* const* d_in, const int* in_sizes, int n_in,
                              void* d_out, int out_size, void* d_ws, size_t ws_size,
                              hipStream_t stream)
{
    const float* x       = (const float*)d_in[0];
    const float* bias    = (const float*)d_in[1];
    const float* g_gamma = (const float*)d_in[2];
    const float* g_beta  = (const float*)d_in[3];
    const float* b_gamma = (const float*)d_in[4];
    const float* b_beta  = (const float*)d_in[5];
    const float* Wq      = (const float*)d_in[6];
    const float* Wk      = (const float*)d_in[7];
    const float* Wv      = (const float*)d_in[8];
    const float* Wb      = (const float*)d_in[9];
    const float* Wg      = (const float*)d_in[10];
    const float* bg      = (const float*)d_in[11];
    const float* Wout    = (const float*)d_in[12];
    const float* bout    = (const float*)d_in[13];
    float* out = (float*)d_out;

    float* ws   = (float*)d_ws;
    float* q_ws = ws;                    // 1 MB each
    float* k_ws = ws + 262144;
    float* v_ws = ws + 2 * 262144;
    float* g_ws = ws + 3 * 262144;

    hipLaunchKernelGGL(prep_kernel, dim3(256), dim3(256), 0, stream,
                       x, g_gamma, g_beta, Wq, Wk, Wv, Wg, bg,
                       q_ws, k_ws, v_ws, g_ws);
    hipLaunchKernelGGL(fused_kernel, dim3(1024), dim3(256), 0, stream,
                       bias, b_gamma, b_beta, Wb, Wout, bout,
                       q_ws, k_ws, v_ws, g_ws, out);
}